// Round 1
// baseline (128.591 us; speedup 1.0000x reference)
//
#include <hip/hip_runtime.h>

#define HH 1024
#define WW 1024
#define BB 8
#define WORDS_X 16             /* 64-px bit-words per row */

typedef unsigned long long u64;

// ---------------------------------------------------------------------------
// Fused kernel: per 64x64 tile, pack the 74-row x 3-word target halo into bit
// words via wave ballots (no separate pack pass, no bits round-trip), then
//   t_c=0: edge <=> OR of 11x11 window ; t_c=1: edge <=> !(AND of window)
// (exactly 121*t_c != window_sum with zero padding: OOB rows/words = 0),
// then the label-smoothing loss on x.
// Halo re-reads overlap 3.47x but target (32 MiB) is fully L2/L3-resident,
// so HBM target traffic stays ~1x. NO device fences / cross-block atomics
// (r7/r8: per-block __threadfence = ~88us L2-writeback storm; r10: contended
// f32 atomic = +12.7us tail). Coherence via kernel boundary only.
// ---------------------------------------------------------------------------
__global__ __launch_bounds__(256) void ls_fused(const float* __restrict__ x,
                                                const int* __restrict__ tgt,
                                                float* __restrict__ partial) {
    __shared__ u64 s_w[74][3];
    __shared__ u64 s_oh[74], s_ah[74], s_e[64];
    __shared__ float s_red[4];

    const int tid  = threadIdx.x;
    const int lane = tid & 63;
    const int wave = tid >> 6;
    const int b  = blockIdx.z;
    const int ty = blockIdx.y * 64;
    const int wx = blockIdx.x;               // word index == tile col block

    // ---- x loads issued first: 16 px/thread/channel; the first barrier
    // drains vmcnt anyway, so issue order just maximizes overlap. ----
    const int row = tid >> 2;
    const int c0  = (tid & 3) << 4;
    const float* x0p = x + ((size_t)b * 2 + 0) * HH * WW
                         + (size_t)(ty + row) * WW + (wx << 6) + c0;
    const float* x1p = x0p + (size_t)HH * WW;
    float4 xv0[4], xv1[4];
#pragma unroll
    for (int q = 0; q < 4; ++q) xv0[q] = ((const float4*)x0p)[q];
#pragma unroll
    for (int q = 0; q < 4; ++q) xv1[q] = ((const float4*)x1p)[q];

    // ---- Halo pack: 74 rows x 3 words. Each wave owns rows r = wave (mod 4).
    // Per word: one coalesced 256B int load + one ballot. OOB -> 0 (zero pad).
    // valid is wave-uniform, so no divergence inside the ballot. ----
    const int* tb = tgt + ((size_t)b << 20);
    for (int r = wave; r < 74; r += 4) {
        const int gy = ty - 5 + r;
        const bool rowok = ((unsigned)gy < HH);
        const int* rp = tb + (size_t)(rowok ? gy : 0) * WW + lane;
        u64 m[3];
#pragma unroll
        for (int k = 0; k < 3; ++k) {
            const int wi = wx - 1 + k;
            const bool valid = rowok & ((unsigned)wi < WORDS_X);
            int v = rp[(valid ? wi : 0) << 6];
            if (!valid) v = 0;
            m[k] = __ballot(v != 0);
        }
        if (lane == 0) {
            s_w[r][0] = m[0]; s_w[r][1] = m[1]; s_w[r][2] = m[2];
        }
    }
    __syncthreads();

    // ---- Horizontal 11-window OR/AND (funnel shift over 192 bits) ----
    if (tid < 74) {
        u64 wl = s_w[tid][0], wm = s_w[tid][1], wr = s_w[tid][2];
        u64 oh = wm, ah = wm;
#pragma unroll
        for (int d = 1; d <= 5; ++d) {
            u64 vr = (wm >> d) | (wr << (64 - d));
            u64 vl = (wm << d) | (wl >> (64 - d));
            oh |= vr | vl;
            ah &= vr & vl;
        }
        s_oh[tid] = oh;
        s_ah[tid] = ah;
    }
    __syncthreads();

    // ---- Vertical 11-window; per-row edge word ----
    if (tid < 64) {
        u64 ov = 0, av = ~0ULL;
#pragma unroll
        for (int k = 0; k < 11; ++k) { ov |= s_oh[tid + k]; av &= s_ah[tid + k]; }
        u64 tc = s_w[tid + 5][1];
        s_e[tid] = (ov & ~tc) | (~av & tc);
    }
    __syncthreads();

    // ---- Loss: 16 px/thread (identical math/order to the verified kernel) ----
    unsigned int e16 = (unsigned int)(s_e[row] >> c0) & 0xffffu;
    unsigned int t16 = (unsigned int)(s_w[row + 5][1] >> c0) & 0xffffu;

    const float* f0 = (const float*)xv0;
    const float* f1 = (const float*)xv1;
    float acc = 0.f;
#pragma unroll
    for (int j = 0; j < 16; ++j) {
        int t = (t16 >> j) & 1;
        int e = (e16 >> j) & 1;
        float v0 = f0[j], v1 = f1[j];
        float m   = fmaxf(v0, v1);
        float lse = m + __logf(1.0f + __expf(-fabsf(v0 - v1)));
        float lp0 = v0 - lse, lp1 = v1 - lse;
        float lpt = t ? lp1 : lp0;
        float lpo = t ? lp0 : lp1;
        acc += e ? (0.95f * lpt + 0.1f * lpo) : lpt;
    }

#pragma unroll
    for (int off = 32; off > 0; off >>= 1) acc += __shfl_down(acc, off, 64);
    if ((tid & 63) == 0) s_red[tid >> 6] = acc;
    __syncthreads();
    if (tid == 0) {
        int bid = (blockIdx.z * gridDim.y + blockIdx.y) * gridDim.x + blockIdx.x;
        partial[bid] = s_red[0] + s_red[1] + s_red[2] + s_red[3];
    }
}

__global__ __launch_bounds__(1024) void ls_final(const float* __restrict__ partial,
                                                 float* __restrict__ out) {
    __shared__ double s_red[16];
    const int tid = threadIdx.x;
    double s = (double)partial[tid] + (double)partial[tid + 1024];
#pragma unroll
    for (int off = 32; off > 0; off >>= 1) s += __shfl_down(s, off, 64);
    if ((tid & 63) == 0) s_red[tid >> 6] = s;
    __syncthreads();
    if (tid == 0) {
        double total = 0.0;
#pragma unroll
        for (int i = 0; i < 16; ++i) total += s_red[i];
        out[0] = (float)(-total * (1.0 / (8.0 * 1024.0 * 1024.0)));
    }
}

extern "C" void kernel_launch(void* const* d_in, const int* in_sizes, int n_in,
                              void* d_out, int out_size, void* d_ws, size_t ws_size,
                              hipStream_t stream) {
    const float* x  = (const float*)d_in[0];
    const int* tgt  = (const int*)d_in[1];

    float* partial = (float*)d_ws;           // 2048 floats

    hipLaunchKernelGGL(ls_fused, dim3(16, 16, 8), dim3(256), 0, stream, x, tgt, partial);
    hipLaunchKernelGGL(ls_final, dim3(1), dim3(1024), 0, stream, partial, (float*)d_out);
}

// Round 2
// 123.564 us; speedup vs baseline: 1.0407x; 1.0407x over previous
//
#include <hip/hip_runtime.h>

#define HH 1024
#define WW 1024
#define BB 8
#define WORDS_X 16             /* 64-px bit-words per row */

typedef unsigned long long u64;

// ---------------------------------------------------------------------------
// Kernel 1: pack target (int32 0/1) into a bit image. Pure stream: per wave,
// 8 independent coalesced 256B loads -> 8 ballots -> one 64B store.
// Measured at its 32MB-read roofline (~5us); do not touch.
// ---------------------------------------------------------------------------
__global__ __launch_bounds__(256) void ls_pack(const int* __restrict__ tgt,
                                               u64* __restrict__ bits) {
    const int lane = threadIdx.x & 63;
    const size_t wv = ((size_t)blockIdx.x * 256 + threadIdx.x) >> 6;
    const size_t wbase = wv * 8;                 // first of 8 words (512 px)
    const int* p = tgt + wbase * 64 + lane;

    int v[8];
#pragma unroll
    for (int j = 0; j < 8; ++j) v[j] = p[j * 64];

    u64 mine = 0;
#pragma unroll
    for (int j = 0; j < 8; ++j) {
        u64 m = __ballot(v[j] != 0);
        if (lane == j) mine = m;
    }
    if (lane < 8) bits[wbase + lane] = mine;
}

// ---------------------------------------------------------------------------
// Kernel 2: edge words from bit image (1MB -> 1MB, L2-resident).
//   t_c=0: edge <=> OR of 11x11 window ; t_c=1: edge <=> !(AND of window)
// (exactly 121*t_c != window_sum with zero padding: OOB rows/words = 0.)
// Per block: 16-row full-width slab; stage 26 rows x 16 words, horizontal
// funnel-shift OR/AND, vertical 11-window, store 16x16 edge words.
// ---------------------------------------------------------------------------
__global__ __launch_bounds__(256) void ls_edge(const u64* __restrict__ bits,
                                               u64* __restrict__ ebits) {
    __shared__ u64 s_b[26][17], s_oh[26][17], s_ah[26][17];  // +1 pad: no 4-way bank alias
    const int tid  = threadIdx.x;
    const int slab = blockIdx.x;      // 0..63
    const int b    = blockIdx.y;      // 0..7
    const int y0   = slab << 4;

    // ---- Stage 26 rows x 16 words (OOB rows -> 0) ----
#pragma unroll
    for (int i = tid; i < 416; i += 256) {
        int r = i >> 4, k = i & 15;
        int gy = y0 - 5 + r;
        u64 v = 0;
        if ((unsigned)gy < HH) v = bits[((size_t)(b << 10) + gy) * WORDS_X + k];
        s_b[r][k] = v;
    }
    __syncthreads();

    // ---- Horizontal 11-window OR/AND (funnel shift; word-edge neighbors = 0) ----
#pragma unroll
    for (int i = tid; i < 416; i += 256) {
        int r = i >> 4, k = i & 15;
        u64 wm = s_b[r][k];
        u64 wl = k ? s_b[r][k - 1] : 0;
        u64 wr = (k < 15) ? s_b[r][k + 1] : 0;
        u64 oh = wm, ah = wm;
#pragma unroll
        for (int d = 1; d <= 5; ++d) {
            u64 vr = (wm >> d) | (wr << (64 - d));
            u64 vl = (wm << d) | (wl >> (64 - d));
            oh |= vr | vl;
            ah &= vr & vl;
        }
        s_oh[r][k] = oh;
        s_ah[r][k] = ah;
    }
    __syncthreads();

    // ---- Vertical 11-window; one output word per thread ----
    {
        int r = tid >> 4, k = tid & 15;   // r: 0..15 within slab
        u64 ov = 0, av = ~0ULL;
#pragma unroll
        for (int j = 0; j < 11; ++j) { ov |= s_oh[r + j][k]; av &= s_ah[r + j][k]; }
        u64 tc = s_b[r + 5][k];
        ebits[((size_t)(b << 10) + y0 + r) * WORDS_X + k] = (ov & ~tc) | (~av & tc);
    }
}

// ---------------------------------------------------------------------------
// Kernel 3: pure streaming loss. NO barriers before the reduction, no LDS
// staging, no dependent-load chains: 8 independent float4 loads + 2 ushort
// mask loads per thread. Same pixel->thread->block grouping and accumulation
// order as the verified absmax=0.0 kernel.
// ---------------------------------------------------------------------------
__global__ __launch_bounds__(256) void ls_loss2(const float* __restrict__ x,
                                                const u64* __restrict__ bits,
                                                const u64* __restrict__ ebits,
                                                float* __restrict__ partial) {
    __shared__ float s_red[4];
    const int tid = threadIdx.x;
    const int b  = blockIdx.z;
    const int ty = blockIdx.y * 64;
    const int wx = blockIdx.x;
    const int row = tid >> 2;
    const int c0  = (tid & 3) << 4;

    const float* x0p = x + ((size_t)b * 2) * HH * WW
                         + (size_t)(ty + row) * WW + (wx << 6) + c0;
    const float* x1p = x0p + (size_t)HH * WW;
    float4 xv0[4], xv1[4];
#pragma unroll
    for (int q = 0; q < 4; ++q) xv0[q] = ((const float4*)x0p)[q];
#pragma unroll
    for (int q = 0; q < 4; ++q) xv1[q] = ((const float4*)x1p)[q];

    // 16-px masks: little-endian u64 words -> ushort lanes line up with px.
    const size_t us = ((size_t)(b << 10) + ty + row) * (WORDS_X * 4)
                    + (wx << 2) + (tid & 3);
    const unsigned int t16 = ((const unsigned short*)bits)[us];
    const unsigned int e16 = ((const unsigned short*)ebits)[us];

    const float* f0 = (const float*)xv0;
    const float* f1 = (const float*)xv1;
    float acc = 0.f;
#pragma unroll
    for (int j = 0; j < 16; ++j) {
        int t = (t16 >> j) & 1;
        int e = (e16 >> j) & 1;
        float v0 = f0[j], v1 = f1[j];
        float m   = fmaxf(v0, v1);
        float lse = m + __logf(1.0f + __expf(-fabsf(v0 - v1)));
        float lp0 = v0 - lse, lp1 = v1 - lse;
        float lpt = t ? lp1 : lp0;
        float lpo = t ? lp0 : lp1;
        acc += e ? (0.95f * lpt + 0.1f * lpo) : lpt;
    }

#pragma unroll
    for (int off = 32; off > 0; off >>= 1) acc += __shfl_down(acc, off, 64);
    if ((tid & 63) == 0) s_red[tid >> 6] = acc;
    __syncthreads();
    if (tid == 0) {
        int bid = (blockIdx.z * gridDim.y + blockIdx.y) * gridDim.x + blockIdx.x;
        partial[bid] = s_red[0] + s_red[1] + s_red[2] + s_red[3];
    }
}

__global__ __launch_bounds__(1024) void ls_final(const float* __restrict__ partial,
                                                 float* __restrict__ out) {
    __shared__ double s_red[16];
    const int tid = threadIdx.x;
    double s = (double)partial[tid] + (double)partial[tid + 1024];
#pragma unroll
    for (int off = 32; off > 0; off >>= 1) s += __shfl_down(s, off, 64);
    if ((tid & 63) == 0) s_red[tid >> 6] = s;
    __syncthreads();
    if (tid == 0) {
        double total = 0.0;
#pragma unroll
        for (int i = 0; i < 16; ++i) total += s_red[i];
        out[0] = (float)(-total * (1.0 / (8.0 * 1024.0 * 1024.0)));
    }
}

extern "C" void kernel_launch(void* const* d_in, const int* in_sizes, int n_in,
                              void* d_out, int out_size, void* d_ws, size_t ws_size,
                              hipStream_t stream) {
    const float* x  = (const float*)d_in[0];
    const int* tgt  = (const int*)d_in[1];

    // ws: [partials 8KB][bits @16KB, 1MB][ebits @16KB+1MB, 1MB]
    float* partial = (float*)d_ws;
    u64* bits  = (u64*)((char*)d_ws + (16 << 10));
    u64* ebits = (u64*)((char*)d_ws + (16 << 10) + (1 << 20));

    hipLaunchKernelGGL(ls_pack, dim3(4096), dim3(256), 0, stream, tgt, bits);
    hipLaunchKernelGGL(ls_edge, dim3(64, 8), dim3(256), 0, stream, bits, ebits);
    hipLaunchKernelGGL(ls_loss2, dim3(16, 16, 8), dim3(256), 0, stream,
                       x, bits, ebits, partial);
    hipLaunchKernelGGL(ls_final, dim3(1), dim3(1024), 0, stream, partial, (float*)d_out);
}

// Round 3
// 121.671 us; speedup vs baseline: 1.0569x; 1.0156x over previous
//
#include <hip/hip_runtime.h>

#define HH 1024
#define WW 1024
#define BB 8
#define WORDS_X 16             /* 64-px bit-words per row */

typedef unsigned long long u64;

// ---------------------------------------------------------------------------
// Kernel 1: pack target (int32 0/1) into a bit image. Pure stream: per wave,
// 8 independent coalesced 256B loads -> 8 ballots -> one 64B store.
// At its 32MB-read roofline (~5us); do not touch.
// ---------------------------------------------------------------------------
__global__ __launch_bounds__(256) void ls_pack(const int* __restrict__ tgt,
                                               u64* __restrict__ bits) {
    const int lane = threadIdx.x & 63;
    const size_t wv = ((size_t)blockIdx.x * 256 + threadIdx.x) >> 6;
    const size_t wbase = wv * 8;                 // first of 8 words (512 px)
    const int* p = tgt + wbase * 64 + lane;

    int v[8];
#pragma unroll
    for (int j = 0; j < 8; ++j) v[j] = p[j * 64];

    u64 mine = 0;
#pragma unroll
    for (int j = 0; j < 8; ++j) {
        u64 m = __ballot(v[j] != 0);
        if (lane == j) mine = m;
    }
    if (lane < 8) bits[wbase + lane] = mine;
}

// ---------------------------------------------------------------------------
// Kernel 2: edge words from bit image (1MB -> 1MB, L2-resident).
//   t_c=0: edge <=> OR of 11x11 window ; t_c=1: edge <=> !(AND of window)
// (exactly 121*t_c != window_sum with zero padding: OOB rows/words = 0.)
// ---------------------------------------------------------------------------
__global__ __launch_bounds__(256) void ls_edge(const u64* __restrict__ bits,
                                               u64* __restrict__ ebits) {
    __shared__ u64 s_b[26][17], s_oh[26][17], s_ah[26][17];  // +1 pad
    const int tid  = threadIdx.x;
    const int slab = blockIdx.x;      // 0..63
    const int b    = blockIdx.y;      // 0..7
    const int y0   = slab << 4;

#pragma unroll
    for (int i = tid; i < 416; i += 256) {
        int r = i >> 4, k = i & 15;
        int gy = y0 - 5 + r;
        u64 v = 0;
        if ((unsigned)gy < HH) v = bits[((size_t)(b << 10) + gy) * WORDS_X + k];
        s_b[r][k] = v;
    }
    __syncthreads();

#pragma unroll
    for (int i = tid; i < 416; i += 256) {
        int r = i >> 4, k = i & 15;
        u64 wm = s_b[r][k];
        u64 wl = k ? s_b[r][k - 1] : 0;
        u64 wr = (k < 15) ? s_b[r][k + 1] : 0;
        u64 oh = wm, ah = wm;
#pragma unroll
        for (int d = 1; d <= 5; ++d) {
            u64 vr = (wm >> d) | (wr << (64 - d));
            u64 vl = (wm << d) | (wl >> (64 - d));
            oh |= vr | vl;
            ah &= vr & vl;
        }
        s_oh[r][k] = oh;
        s_ah[r][k] = ah;
    }
    __syncthreads();

    {
        int r = tid >> 4, k = tid & 15;   // r: 0..15 within slab
        u64 ov = 0, av = ~0ULL;
#pragma unroll
        for (int j = 0; j < 11; ++j) { ov |= s_oh[r + j][k]; av &= s_ah[r + j][k]; }
        u64 tc = s_b[r + 5][k];
        ebits[((size_t)(b << 10) + y0 + r) * WORDS_X + k] = (ov & ~tc) | (~av & tc);
    }
}

// ---------------------------------------------------------------------------
// Kernel 3: streaming loss, LANE-CONTIGUOUS loads.
// R2 lesson: the old (row=tid>>2, c0=(tid&3)*16) mapping made every vmem
// instruction scatter 64 lanes over 64 discontiguous 16B sectors (16B used
// per 64B region) -> TA/sector-request bound at ~2.3 TB/s, VALUBusy 33%,
// HBM 25% (nothing saturated). New mapping: float4 chunk f = q*256 + tid of
// the 64x64 tile; per instruction, 16 lanes cover one full 256B row, a wave
// covers 4 consecutive rows -> fully merged lines. Masks: one u64 word per
// row, 16 lanes share the address (broadcast, L2-resident).
// Per-thread px regrouping (4x4 vs 16x1) perturbs the f32 sum order; final
// scalar deviation ~1e-9 after f64 normalize.
// ---------------------------------------------------------------------------
__global__ __launch_bounds__(256) void ls_loss2(const float* __restrict__ x,
                                                const u64* __restrict__ bits,
                                                const u64* __restrict__ ebits,
                                                float* __restrict__ partial) {
    __shared__ float s_red[4];
    const int tid = threadIdx.x;
    const int b  = blockIdx.z;
    const int ty = blockIdx.y * 64;
    const int wx = blockIdx.x;

    const float* xb0 = x + ((size_t)b * 2) * HH * WW + (size_t)ty * WW + (wx << 6);
    const float* xb1 = xb0 + (size_t)HH * WW;
    const u64* tw = bits  + ((size_t)(b << 10) + ty) * WORDS_X + wx;
    const u64* ew = ebits + ((size_t)(b << 10) + ty) * WORDS_X + wx;

    const int r0 = tid >> 4;          // 0..15, +16 per q
    const int c4 = tid & 15;          // float4 index within row
    const int sh = c4 << 2;           // bit position of this 4-px nibble

    float4 v0[4], v1[4];
    u64 twv[4], ewv[4];
#pragma unroll
    for (int q = 0; q < 4; ++q) {
        const size_t r = (size_t)(r0 + (q << 4));
        v0[q] = ((const float4*)(xb0 + r * WW))[c4];
        v1[q] = ((const float4*)(xb1 + r * WW))[c4];
        twv[q] = tw[r * WORDS_X];
        ewv[q] = ew[r * WORDS_X];
    }

    float acc = 0.f;
#pragma unroll
    for (int q = 0; q < 4; ++q) {
        const unsigned t4 = (unsigned)(twv[q] >> sh) & 0xfu;
        const unsigned e4 = (unsigned)(ewv[q] >> sh) & 0xfu;
        const float* f0 = (const float*)&v0[q];
        const float* f1 = (const float*)&v1[q];
#pragma unroll
        for (int j = 0; j < 4; ++j) {
            int t = (t4 >> j) & 1;
            int e = (e4 >> j) & 1;
            float a0 = f0[j], a1 = f1[j];
            float m   = fmaxf(a0, a1);
            float lse = m + __logf(1.0f + __expf(-fabsf(a0 - a1)));
            float lp0 = a0 - lse, lp1 = a1 - lse;
            float lpt = t ? lp1 : lp0;
            float lpo = t ? lp0 : lp1;
            acc += e ? (0.95f * lpt + 0.1f * lpo) : lpt;
        }
    }

#pragma unroll
    for (int off = 32; off > 0; off >>= 1) acc += __shfl_down(acc, off, 64);
    if ((tid & 63) == 0) s_red[tid >> 6] = acc;
    __syncthreads();
    if (tid == 0) {
        int bid = (blockIdx.z * gridDim.y + blockIdx.y) * gridDim.x + blockIdx.x;
        partial[bid] = s_red[0] + s_red[1] + s_red[2] + s_red[3];
    }
}

__global__ __launch_bounds__(1024) void ls_final(const float* __restrict__ partial,
                                                 float* __restrict__ out) {
    __shared__ double s_red[16];
    const int tid = threadIdx.x;
    double s = (double)partial[tid] + (double)partial[tid + 1024];
#pragma unroll
    for (int off = 32; off > 0; off >>= 1) s += __shfl_down(s, off, 64);
    if ((tid & 63) == 0) s_red[tid >> 6] = s;
    __syncthreads();
    if (tid == 0) {
        double total = 0.0;
#pragma unroll
        for (int i = 0; i < 16; ++i) total += s_red[i];
        out[0] = (float)(-total * (1.0 / (8.0 * 1024.0 * 1024.0)));
    }
}

extern "C" void kernel_launch(void* const* d_in, const int* in_sizes, int n_in,
                              void* d_out, int out_size, void* d_ws, size_t ws_size,
                              hipStream_t stream) {
    const float* x  = (const float*)d_in[0];
    const int* tgt  = (const int*)d_in[1];

    // ws: [partials 8KB][bits @16KB, 1MB][ebits @16KB+1MB, 1MB]
    float* partial = (float*)d_ws;
    u64* bits  = (u64*)((char*)d_ws + (16 << 10));
    u64* ebits = (u64*)((char*)d_ws + (16 << 10) + (1 << 20));

    hipLaunchKernelGGL(ls_pack, dim3(4096), dim3(256), 0, stream, tgt, bits);
    hipLaunchKernelGGL(ls_edge, dim3(64, 8), dim3(256), 0, stream, bits, ebits);
    hipLaunchKernelGGL(ls_loss2, dim3(16, 16, 8), dim3(256), 0, stream,
                       x, bits, ebits, partial);
    hipLaunchKernelGGL(ls_final, dim3(1), dim3(1024), 0, stream, partial, (float*)d_out);
}